// Round 1
// baseline (1099.435 us; speedup 1.0000x reference)
//
#include <hip/hip_runtime.h>
#include <hip/hip_bf16.h>
#include <math.h>

// Problem constants (from reference)
#define N_NODES  1000000
#define C_IN     128
#define HID      32
#define OUTF     16
#define NSRC1    600000
#define NDST1    80000
#define E1       1280000
#define NDST2    8000
#define E2       80000

// ---------------------------------------------------------------------------
// K1: p[s] = x[n_id[s]] @ W1   for s in [0, NSRC1)
// Block = 256 (8 groups of 32 lanes). Each group handles 4 rows at a time;
// lane o computes output column o for all 4 rows. W1 staged in LDS as
// float4[k4][o] so the b128 LDS read is conflict-free and each W read is
// reused for 4 rows (amortizes LDS BW below VALU cost).
// ---------------------------------------------------------------------------
__global__ __launch_bounds__(256) void k1_transform(
    const float* __restrict__ x, const int* __restrict__ n_id,
    const float* __restrict__ W1, float* __restrict__ p)
{
    __shared__ float4 w4[32 * 32];  // [k4][o] ; w4[k4*32+o] = W1[4k4..4k4+3][o]
    float* w4f = (float*)w4;
    for (int idx = threadIdx.x; idx < C_IN * HID; idx += 256) {
        int k = idx >> 5, o = idx & 31;             // W1 row-major: idx = k*32+o
        w4f[(((k >> 2) * 32 + o) << 2) + (k & 3)] = W1[idx];
    }
    __syncthreads();

    const int group = blockIdx.x * 8 + (threadIdx.x >> 5);  // [0, 150000)
    const int o = threadIdx.x & 31;
    const int s0 = group * 4;                                // NSRC1 % 4 == 0

    const float4* x0 = (const float4*)(x + (size_t)n_id[s0 + 0] * C_IN);
    const float4* x1 = (const float4*)(x + (size_t)n_id[s0 + 1] * C_IN);
    const float4* x2 = (const float4*)(x + (size_t)n_id[s0 + 2] * C_IN);
    const float4* x3 = (const float4*)(x + (size_t)n_id[s0 + 3] * C_IN);

    float a0 = 0.f, a1 = 0.f, a2 = 0.f, a3 = 0.f;
    #pragma unroll 8
    for (int k4 = 0; k4 < 32; ++k4) {
        float4 wv = w4[k4 * 32 + o];
        float4 v0 = x0[k4];
        float4 v1 = x1[k4];
        float4 v2 = x2[k4];
        float4 v3 = x3[k4];
        a0 += v0.x * wv.x + v0.y * wv.y + v0.z * wv.z + v0.w * wv.w;
        a1 += v1.x * wv.x + v1.y * wv.y + v1.z * wv.z + v1.w * wv.w;
        a2 += v2.x * wv.x + v2.y * wv.y + v2.z * wv.z + v2.w * wv.w;
        a3 += v3.x * wv.x + v3.y * wv.y + v3.z * wv.z + v3.w * wv.w;
    }
    p[(size_t)(s0 + 0) * HID + o] = a0;
    p[(size_t)(s0 + 1) * HID + o] = a1;
    p[(size_t)(s0 + 2) * HID + o] = a2;
    p[(size_t)(s0 + 3) * HID + o] = a3;
}

// ---------------------------------------------------------------------------
// K2: scatter layer-1 messages. 32 lanes per edge (one per feature).
// agg1[dst1[e]][f] += p[src1[e]][f] ; cnt1[dst1[e]] += 1
// ---------------------------------------------------------------------------
__global__ __launch_bounds__(256) void k2_scatter1(
    const int* __restrict__ src1, const int* __restrict__ dst1,
    const float* __restrict__ p, float* __restrict__ agg1,
    float* __restrict__ cnt1)
{
    const int gid = blockIdx.x * 256 + threadIdx.x;
    const int e = gid >> 5;
    const int f = gid & 31;
    if (e >= E1) return;
    const int s = src1[e];
    const int d = dst1[e];
    atomicAdd(&agg1[(size_t)d * HID + f], p[(size_t)s * HID + f]);
    if (f == 0) atomicAdd(&cnt1[d], 1.0f);
}

// ---------------------------------------------------------------------------
// K3: q[d] = relu(agg1[d]/max(cnt1[d],1) + b1) @ W2   for d in [0, NDST1)
// 16 threads per d (one per output column).
// ---------------------------------------------------------------------------
__global__ __launch_bounds__(256) void k3_finalize1(
    const float* __restrict__ agg1, const float* __restrict__ cnt1,
    const float* __restrict__ b1, const float* __restrict__ W2,
    float* __restrict__ q)
{
    __shared__ float w2s[HID * OUTF];
    __shared__ float b1s[HID];
    for (int i = threadIdx.x; i < HID * OUTF; i += 256) w2s[i] = W2[i];
    if (threadIdx.x < HID) b1s[threadIdx.x] = b1[threadIdx.x];
    __syncthreads();

    const int gid = blockIdx.x * 256 + threadIdx.x;
    const int d = gid >> 4;
    const int j = gid & 15;
    if (d >= NDST1) return;

    const float inv = 1.0f / fmaxf(cnt1[d], 1.0f);
    float acc = 0.f;
    #pragma unroll
    for (int i = 0; i < HID; ++i) {
        float a = fmaxf(agg1[(size_t)d * HID + i] * inv + b1s[i], 0.f);
        acc += a * w2s[i * OUTF + j];
    }
    q[(size_t)d * OUTF + j] = acc;
}

// ---------------------------------------------------------------------------
// K4: scatter layer-2 messages. 16 lanes per edge.
// ---------------------------------------------------------------------------
__global__ __launch_bounds__(256) void k4_scatter2(
    const int* __restrict__ src2, const int* __restrict__ dst2,
    const float* __restrict__ q, float* __restrict__ agg2,
    float* __restrict__ cnt2)
{
    const int gid = blockIdx.x * 256 + threadIdx.x;
    const int e = gid >> 4;
    const int f = gid & 15;
    if (e >= E2) return;
    const int s = src2[e];
    const int d = dst2[e];
    atomicAdd(&agg2[(size_t)d * OUTF + f], q[(size_t)s * OUTF + f]);
    if (f == 0) atomicAdd(&cnt2[d], 1.0f);
}

// ---------------------------------------------------------------------------
// K5: out[v] = log_softmax(agg2[v]/max(cnt2[v],1) + b2). One thread per v.
// ---------------------------------------------------------------------------
__global__ __launch_bounds__(256) void k5_logsoftmax(
    const float* __restrict__ agg2, const float* __restrict__ cnt2,
    const float* __restrict__ b2, float* __restrict__ out)
{
    const int v = blockIdx.x * 256 + threadIdx.x;
    if (v >= NDST2) return;
    const float inv = 1.0f / fmaxf(cnt2[v], 1.0f);
    float z[OUTF];
    float m = -INFINITY;
    #pragma unroll
    for (int j = 0; j < OUTF; ++j) {
        z[j] = agg2[(size_t)v * OUTF + j] * inv + b2[j];
        m = fmaxf(m, z[j]);
    }
    float s = 0.f;
    #pragma unroll
    for (int j = 0; j < OUTF; ++j) s += expf(z[j] - m);
    const float lse = m + logf(s);
    #pragma unroll
    for (int j = 0; j < OUTF; ++j) out[(size_t)v * OUTF + j] = z[j] - lse;
}

// ---------------------------------------------------------------------------
// Workspace layout (bytes):
//   p    @ 0          : 600000*32*4 = 76,800,000
//   agg1 @ 76,800,000 : 80000*32*4  = 10,240,000
//   cnt1 @ 87,040,000 : 80000*4     =    320,000
//   agg2 @ 87,360,000 : 8000*16*4   =    512,000
//   cnt2 @ 87,872,000 : 8000*4      =     32,000
//   q    @ 87,904,000 : 80000*16*4  =  5,120,000   (total ~93 MB)
// agg1..cnt2 are contiguous -> single memset of 11,104,000 B.
// ---------------------------------------------------------------------------
extern "C" void kernel_launch(void* const* d_in, const int* in_sizes, int n_in,
                              void* d_out, int out_size, void* d_ws, size_t ws_size,
                              hipStream_t stream)
{
    const float* x    = (const float*)d_in[0];
    const int*   n_id = (const int*)  d_in[1];
    const int*   src1 = (const int*)  d_in[2];
    const int*   dst1 = (const int*)  d_in[3];
    const int*   src2 = (const int*)  d_in[4];
    const int*   dst2 = (const int*)  d_in[5];
    const float* W1   = (const float*)d_in[6];
    const float* b1   = (const float*)d_in[7];
    const float* W2   = (const float*)d_in[8];
    const float* b2   = (const float*)d_in[9];
    float* out = (float*)d_out;

    char* ws = (char*)d_ws;
    float* p    = (float*)(ws + 0);
    float* agg1 = (float*)(ws + 76800000);
    float* cnt1 = (float*)(ws + 87040000);
    float* agg2 = (float*)(ws + 87360000);
    float* cnt2 = (float*)(ws + 87872000);
    float* q    = (float*)(ws + 87904000);

    // zero the accumulation region (agg1, cnt1, agg2, cnt2 are contiguous)
    hipMemsetAsync(agg1, 0, 11104000, stream);

    k1_transform <<<NSRC1 / 32, 256, 0, stream>>>(x, n_id, W1, p);
    k2_scatter1  <<<(E1 * 32 + 255) / 256, 256, 0, stream>>>(src1, dst1, p, agg1, cnt1);
    k3_finalize1 <<<(NDST1 * 16 + 255) / 256, 256, 0, stream>>>(agg1, cnt1, b1, W2, q);
    k4_scatter2  <<<(E2 * 16 + 255) / 256, 256, 0, stream>>>(src2, dst2, q, agg2, cnt2);
    k5_logsoftmax<<<(NDST2 + 255) / 256, 256, 0, stream>>>(agg2, cnt2, b2, out);
}